// Round 19
// baseline (141.703 us; speedup 1.0000x reference)
//
#include <hip/hip_runtime.h>
#include <hip/hip_bf16.h>

typedef unsigned short u16;
typedef unsigned int u32;
typedef __attribute__((ext_vector_type(2))) unsigned int u32x2;
typedef __attribute__((ext_vector_type(8))) short s16x8;
typedef __attribute__((ext_vector_type(4))) float f32x4;
typedef __attribute__((ext_vector_type(16))) float f32x16;

#define NB 2
#define NH 16
#define NS 2048
#define ND 1024
#define QSCALE 0.1803368801111244f  // 0.125 * log2(e)  (exp2-domain softmax)
#define MFIX 8.0f                   // fixed softmax reference point (exp2 dom)

#define AS1(p) ((const __attribute__((address_space(1))) void*)(p))
#define AS3(p) ((__attribute__((address_space(3))) void*)(p))

__device__ __forceinline__ u16 f2bf(float f) {
  u32 u = __float_as_uint(f);
  u = u + 0x7FFFu + ((u >> 16) & 1u);
  return (u16)(u >> 16);
}

__device__ __forceinline__ float bf2f(u16 h) {
  return __uint_as_float(((u32)h) << 16);
}

__device__ __forceinline__ u32 pkbf(float a, float b) {
  __hip_bfloat162 h = __float22bfloat162_rn(make_float2(a, b));
  union { __hip_bfloat162 h; u32 u; } cv;
  cv.h = h;
  return cv.u;
}

// ---------------------------------------------------------------------------
// fp32 -> bf16 conversion, 16 uniform 1M-element slices.
// ---------------------------------------------------------------------------
__global__ __launch_bounds__(256) void cvt_kernel(
    const float* __restrict__ q, const float* __restrict__ k,
    const float* __restrict__ v, const float* __restrict__ wq,
    const float* __restrict__ wk, const float* __restrict__ wv,
    const float* __restrict__ wo, u16* __restrict__ Xbf,
    u16* __restrict__ Wbf) {
  const int s = blockIdx.z;
  const size_t M1 = (size_t)1024 * 1024;
  const float* src;
  u16* dst;
  if (s < 4)       { src = q + (size_t)s * M1;        dst = Xbf + (size_t)s * M1; }
  else if (s < 8)  { src = k + (size_t)(s - 4) * M1;  dst = Xbf + (size_t)s * M1; }
  else if (s < 12) { src = v + (size_t)(s - 8) * M1;  dst = Xbf + (size_t)s * M1; }
  else if (s == 12){ src = wq; dst = Wbf; }
  else if (s == 13){ src = wk; dst = Wbf + M1; }
  else if (s == 14){ src = wv; dst = Wbf + 2 * M1; }
  else             { src = wo; dst = Wbf + 3 * M1; }
  const int n4 = 1024 * 1024 / 4;
  for (int i = blockIdx.x * 256 + threadIdx.x; i < n4; i += gridDim.x * 256) {
    float4 a = ((const float4*)src)[i];
    uint2 p;
    p.x = (u32)f2bf(a.x) | ((u32)f2bf(a.y) << 16);
    p.y = (u32)f2bf(a.z) | ((u32)f2bf(a.w) << 16);
    ((uint2*)dst)[i] = p;
  }
}

// ---------------------------------------------------------------------------
// 64x128 GEMM tile, T4 counted-vmcnt 2-deep pipeline. Grid 1536 blocks ->
// 6 blocks/CU (was 3): the r17 occupancy lever applied to the GEMM.
// Waves 2x2 over the tile: wr=(w>>1)*32, wc=(w&1)*64, acc[2][4].
// Staging per tile: A = 256 slots (c0 only), B = 512 slots (c0,c1); 3 loads.
// ---------------------------------------------------------------------------
__global__ __launch_bounds__(256) void gemm_qkv_fast(
    const u16* __restrict__ Xbf, const u16* __restrict__ Wbf,
    const float* __restrict__ bq, const float* __restrict__ bk,
    const float* __restrict__ bv, u16* __restrict__ qh, u16* __restrict__ kh,
    u16* __restrict__ vT) {
  const int which = blockIdx.z;
  const int m0 = blockIdx.y * 64, n0 = blockIdx.x * 128;
  const u16* A = Xbf + (size_t)which * 4096 * 1024;
  const u16* B = Wbf + (size_t)which * 1024 * 1024;
  const float* bias = (which == 0) ? bq : (which == 1) ? bk : bv;
  const int tid = threadIdx.x;
  const int w = tid >> 6, l = tid & 63, lr = l & 15, lg = l >> 4;
  const int wr = (w >> 1) * 32, wc = (w & 1) * 64;

  __shared__ u16 As[2][64 * 32];
  __shared__ u16 Bs[2][128 * 32];

  const int c0 = tid, c1 = 256 + tid;
  const int row0 = c0 >> 2, k40 = (c0 & 3) ^ (row0 & 3);
  const int row1 = c1 >> 2, k41 = (c1 & 3) ^ (row1 & 3);
  const u16* saA = A + (size_t)(m0 + row0) * 1024 + k40 * 8;  // A rows 0..63
  const u16* sb0 = B + (size_t)(n0 + row0) * 1024 + k40 * 8;  // B rows 0..63
  const u16* sb1 = B + (size_t)(n0 + row1) * 1024 + k41 * 8;  // B rows 64..127
  const int d0 = (w * 64) * 8, d1 = (256 + w * 64) * 8;  // wave-uniform dests

  const f32x4 fzero = {0.f, 0.f, 0.f, 0.f};
  f32x4 acc[2][4];
#pragma unroll
  for (int m = 0; m < 2; ++m)
#pragma unroll
    for (int n = 0; n < 4; ++n) acc[m][n] = fzero;

  auto STAGE = [&](int buf, int k0) {  // 3 loads per thread
    __builtin_amdgcn_global_load_lds(AS1(saA + k0), AS3(As[buf] + d0), 16, 0, 0);
    __builtin_amdgcn_global_load_lds(AS1(sb0 + k0), AS3(Bs[buf] + d0), 16, 0, 0);
    __builtin_amdgcn_global_load_lds(AS1(sb1 + k0), AS3(Bs[buf] + d1), 16, 0, 0);
  };

  STAGE(0, 0);
  STAGE(1, 32);
  asm volatile("s_waitcnt vmcnt(3)" ::: "memory");  // tile 0 landed
  __builtin_amdgcn_sched_barrier(0);
  __builtin_amdgcn_s_barrier();

  int cur = 0;
  for (int step = 0; step < 32; ++step) {
    s16x8 af[2], bf[4];
#pragma unroll
    for (int m = 0; m < 2; ++m) {
      int row = wr + m * 16 + lr;
      af[m] = *(const s16x8*)(As[cur] + row * 32 + ((lg ^ (row & 3)) * 8));
    }
#pragma unroll
    for (int n = 0; n < 4; ++n) {
      int row = wc + n * 16 + lr;
      bf[n] = *(const s16x8*)(Bs[cur] + row * 32 + ((lg ^ (row & 3)) * 8));
    }
    asm volatile("s_waitcnt lgkmcnt(0)" ::: "memory");
    __builtin_amdgcn_sched_barrier(0);
    __builtin_amdgcn_s_barrier();

    const bool stg = (step + 2 < 32);
    if (stg) STAGE(cur, (step + 2) * 32);

    __builtin_amdgcn_s_setprio(1);
#pragma unroll
    for (int m = 0; m < 2; ++m)
#pragma unroll
      for (int n = 0; n < 4; ++n)
        acc[m][n] = __builtin_amdgcn_mfma_f32_16x16x32_bf16(af[m], bf[n],
                                                            acc[m][n], 0, 0, 0);
    __builtin_amdgcn_s_setprio(0);

    if (stg)
      asm volatile("s_waitcnt vmcnt(3)" ::: "memory");  // t+1 done, t+2 flying
    else
      asm volatile("s_waitcnt vmcnt(0)" ::: "memory");  // tail drain
    __builtin_amdgcn_sched_barrier(0);
    __builtin_amdgcn_s_barrier();
    cur ^= 1;
  }

#pragma unroll
  for (int m = 0; m < 2; ++m) {
#pragma unroll
    for (int n = 0; n < 4; ++n) {
#pragma unroll
      for (int i = 0; i < 4; ++i) {
        int row = m0 + wr + m * 16 + 4 * lg + i;
        int col = n0 + wc + n * 16 + lr;
        float val = acc[m][n][i] + bias[col];
        if (which == 0) val *= QSCALE;
        int bbi = row >> 11, ss = row & 2047;
        int hhd = col >> 6, hd = col & 63;
        if (which == 0) {
          qh[(((size_t)bbi * NH + hhd) * NS + ss) * 64 + hd] = f2bf(val);
        } else if (which == 1) {
          kh[(((size_t)bbi * NH + hhd) * NS + ss) * 64 + hd] = f2bf(val);
        } else {
          vT[(((size_t)bbi * NH + hhd) * 64 + hd) * NS + ss] = f2bf(val);
        }
      }
    }
  }
}

// ---------------------------------------------------------------------------
// Output projection GEMM, same 64x128 tile / 2-deep pipeline. Grid 512
// blocks -> 2 blocks/CU (was 1).
// ---------------------------------------------------------------------------
__global__ __launch_bounds__(256) void gemm_out_fast(
    const u16* __restrict__ zin, const u16* __restrict__ Wbf,
    const float* __restrict__ bo, float* __restrict__ out) {
  const u16* B = Wbf + (size_t)3 * 1024 * 1024;
  const int m0 = blockIdx.y * 64, n0 = blockIdx.x * 128;
  const int tid = threadIdx.x;
  const int w = tid >> 6, l = tid & 63, lr = l & 15, lg = l >> 4;
  const int wr = (w >> 1) * 32, wc = (w & 1) * 64;

  __shared__ u16 As[2][64 * 32];
  __shared__ u16 Bs[2][128 * 32];

  const int c0 = tid, c1 = 256 + tid;
  const int row0 = c0 >> 2, k40 = (c0 & 3) ^ (row0 & 3);
  const int row1 = c1 >> 2, k41 = (c1 & 3) ^ (row1 & 3);
  const u16* saA = zin + (size_t)(m0 + row0) * 1024 + k40 * 8;
  const u16* sb0 = B + (size_t)(n0 + row0) * 1024 + k40 * 8;
  const u16* sb1 = B + (size_t)(n0 + row1) * 1024 + k41 * 8;
  const int d0 = (w * 64) * 8, d1 = (256 + w * 64) * 8;

  const f32x4 fzero = {0.f, 0.f, 0.f, 0.f};
  f32x4 acc[2][4];
#pragma unroll
  for (int m = 0; m < 2; ++m)
#pragma unroll
    for (int n = 0; n < 4; ++n) acc[m][n] = fzero;

  auto STAGE = [&](int buf, int k0) {
    __builtin_amdgcn_global_load_lds(AS1(saA + k0), AS3(As[buf] + d0), 16, 0, 0);
    __builtin_amdgcn_global_load_lds(AS1(sb0 + k0), AS3(Bs[buf] + d0), 16, 0, 0);
    __builtin_amdgcn_global_load_lds(AS1(sb1 + k0), AS3(Bs[buf] + d1), 16, 0, 0);
  };

  STAGE(0, 0);
  STAGE(1, 32);
  asm volatile("s_waitcnt vmcnt(3)" ::: "memory");
  __builtin_amdgcn_sched_barrier(0);
  __builtin_amdgcn_s_barrier();

  int cur = 0;
  for (int step = 0; step < 32; ++step) {
    s16x8 af[2], bf[4];
#pragma unroll
    for (int m = 0; m < 2; ++m) {
      int row = wr + m * 16 + lr;
      af[m] = *(const s16x8*)(As[cur] + row * 32 + ((lg ^ (row & 3)) * 8));
    }
#pragma unroll
    for (int n = 0; n < 4; ++n) {
      int row = wc + n * 16 + lr;
      bf[n] = *(const s16x8*)(Bs[cur] + row * 32 + ((lg ^ (row & 3)) * 8));
    }
    asm volatile("s_waitcnt lgkmcnt(0)" ::: "memory");
    __builtin_amdgcn_sched_barrier(0);
    __builtin_amdgcn_s_barrier();

    const bool stg = (step + 2 < 32);
    if (stg) STAGE(cur, (step + 2) * 32);

    __builtin_amdgcn_s_setprio(1);
#pragma unroll
    for (int m = 0; m < 2; ++m)
#pragma unroll
      for (int n = 0; n < 4; ++n)
        acc[m][n] = __builtin_amdgcn_mfma_f32_16x16x32_bf16(af[m], bf[n],
                                                            acc[m][n], 0, 0, 0);
    __builtin_amdgcn_s_setprio(0);

    if (stg)
      asm volatile("s_waitcnt vmcnt(3)" ::: "memory");
    else
      asm volatile("s_waitcnt vmcnt(0)" ::: "memory");
    __builtin_amdgcn_sched_barrier(0);
    __builtin_amdgcn_s_barrier();
    cur ^= 1;
  }

#pragma unroll
  for (int m = 0; m < 2; ++m)
#pragma unroll
    for (int n = 0; n < 4; ++n)
#pragma unroll
      for (int i = 0; i < 4; ++i) {
        int row = m0 + wr + m * 16 + 4 * lg + i;
        int col = n0 + wc + n * 16 + lr;
        out[(size_t)row * 1024 + col] = acc[m][n][i] + bo[col];
      }
}

// ---------------------------------------------------------------------------
// KV-split causal flash attention, fixed-m softmax, one chunk per block
// (r18, verified): grid 1024 -> 4 blocks/CU.
// ---------------------------------------------------------------------------
__device__ __forceinline__ void stage64(const u16* __restrict__ kh,
                                        const u16* __restrict__ vT, int bh,
                                        int t, int tid, int w, u16* kbase,
                                        u16* vbase) {
#pragma unroll
  for (int i = 0; i < 2; ++i) {
    int c = i * 256 + tid;
    int row = c >> 3, k8 = (c & 7) ^ (row & 7);
    const u16* sk = kh + ((size_t)bh * NS + t * 64 + row) * 64 + k8 * 8;
    const u16* sv = vT + ((size_t)bh * 64 + row) * NS + t * 64 + k8 * 8;
    u16* dk = kbase + (i * 256 + w * 64) * 8;
    u16* dv = vbase + (i * 256 + w * 64) * 8;
    __builtin_amdgcn_global_load_lds(AS1(sk), AS3(dk), 16, 0, 0);
    __builtin_amdgcn_global_load_lds(AS1(sv), AS3(dv), 16, 0, 0);
  }
}

__global__ __launch_bounds__(256) void attn_split_kernel(
    const u16* __restrict__ qh, const u16* __restrict__ kh,
    const u16* __restrict__ vT, u16* __restrict__ Opart,
    float* __restrict__ Lpart) {
  const int f = blockIdx.x;             // 0..1023
  const int len = 16 - (f >> 6);        // 16..1, longest chunks first
  const int idx = f & 63;
  const int bh = idx >> 1;              // 0..31
  const int cc = idx & 1;               // partial slot
  const int band = len - 1;             // q band (128 rows)
  const int t0 = cc ? len : 0;
  const int t1 = t0 + len;
  const int tid = threadIdx.x;
  const int w = tid >> 6, l = tid & 63;
  const int ql = l & 31, hi = l >> 5, hi8 = hi * 8;
  const int q0w = band * 128 + w * 32;

  __shared__ u16 smem[2][2][64][64];  // [buf][K/V][row][64] linear, swizzled

  s16x8 qf[4];
  {
    const u16* qp = qh + ((size_t)bh * NS + q0w + ql) * 64 + hi8;
#pragma unroll
    for (int st = 0; st < 4; ++st) qf[st] = *(const s16x8*)(qp + st * 16);
  }

  f32x16 o0 = {0, 0, 0, 0, 0, 0, 0, 0, 0, 0, 0, 0, 0, 0, 0, 0};
  f32x16 o1 = {0, 0, 0, 0, 0, 0, 0, 0, 0, 0, 0, 0, 0, 0, 0, 0};
  float l_run = 0.f;

  stage64(kh, vT, bh, t0, tid, w, &smem[t0 & 1][0][0][0],
          &smem[t0 & 1][1][0][0]);
  __syncthreads();

  for (int t = t0; t < t1; ++t) {
    if (t + 1 < t1)
      stage64(kh, vT, bh, t + 1, tid, w, &smem[(t + 1) & 1][0][0][0],
              &smem[(t + 1) & 1][1][0][0]);
    const u16* kp = &smem[t & 1][0][0][0];
    const u16* vp = &smem[t & 1][1][0][0];

    const int kvg0 = t * 64, kvg1 = t * 64 + 32;
    if (kvg0 <= q0w) {  // wave-uniform; whole-tile skip only at chunk tail
      f32x16 s0 = {0, 0, 0, 0, 0, 0, 0, 0, 0, 0, 0, 0, 0, 0, 0, 0};
      f32x16 s1 = {0, 0, 0, 0, 0, 0, 0, 0, 0, 0, 0, 0, 0, 0, 0, 0};
      const int kr0 = ql, kr1 = 32 + ql;
      __builtin_amdgcn_s_setprio(1);
#pragma unroll
      for (int st = 0; st < 4; ++st) {
        s16x8 ak = *(const s16x8*)(kp + kr0 * 64 +
                                   (((st * 2 + hi) ^ (kr0 & 7)) * 8));
        s0 = __builtin_amdgcn_mfma_f32_32x32x16_bf16(ak, qf[st], s0, 0, 0, 0);
      }
      if (kvg1 <= q0w) {
#pragma unroll
        for (int st = 0; st < 4; ++st) {
          s16x8 ak = *(const s16x8*)(kp + kr1 * 64 +
                                     (((st * 2 + hi) ^ (kr1 & 7)) * 8));
          s1 = __builtin_amdgcn_mfma_f32_32x32x16_bf16(ak, qf[st], s1, 0, 0,
                                                       0);
        }
      }
      __builtin_amdgcn_s_setprio(0);

      if (kvg0 == q0w) {
#pragma unroll
        for (int r = 0; r < 16; ++r) {
          int kvloc = (r & 3) + 8 * (r >> 2) + 4 * hi;
          if (kvloc > ql) s0[r] = -1e30f;
        }
      }
      if (kvg1 > q0w) {
#pragma unroll
        for (int r = 0; r < 16; ++r) s1[r] = -1e30f;
      } else if (kvg1 == q0w) {
#pragma unroll
        for (int r = 0; r < 16; ++r) {
          int kvloc = (r & 3) + 8 * (r >> 2) + 4 * hi;
          if (kvloc > ql) s1[r] = -1e30f;
        }
      }

      // ---- fixed-m softmax: P = exp2(S - MFIX); no max, no rescale ----
      float ps = 0.f;
      u32 pk0[8], pk1[8];
#pragma unroll
      for (int tt = 0; tt < 8; ++tt) {
        float a = __builtin_amdgcn_exp2f(s0[2 * tt] - MFIX);
        float b = __builtin_amdgcn_exp2f(s0[2 * tt + 1] - MFIX);
        ps += a + b;
        pk0[tt] = pkbf(a, b);
      }
#pragma unroll
      for (int tt = 0; tt < 8; ++tt) {
        float a = __builtin_amdgcn_exp2f(s1[2 * tt] - MFIX);
        float b = __builtin_amdgcn_exp2f(s1[2 * tt + 1] - MFIX);
        ps += a + b;
        pk1[tt] = pkbf(a, b);
      }
      {
        u32x2 rp = __builtin_amdgcn_permlane32_swap(
            __float_as_uint(ps), __float_as_uint(ps), 0, 0);
        ps = __uint_as_float(rp.x) + __uint_as_float(rp.y);
      }
      l_run += ps;

      u32x2 e0 = __builtin_amdgcn_permlane32_swap(pk0[0], pk0[2], 0, 0);
      u32x2 e1 = __builtin_amdgcn_permlane32_swap(pk0[1], pk0[3], 0, 0);
      u32x2 e2 = __builtin_amdgcn_permlane32_swap(pk0[4], pk0[6], 0, 0);
      u32x2 e3 = __builtin_amdgcn_permlane32_swap(pk0[5], pk0[7], 0, 0);
      u32x2 e4 = __builtin_amdgcn_permlane32_swap(pk1[0], pk1[2], 0, 0);
      u32x2 e5 = __builtin_amdgcn_permlane32_swap(pk1[1], pk1[3], 0, 0);
      u32x2 e6 = __builtin_amdgcn_permlane32_swap(pk1[4], pk1[6], 0, 0);
      u32x2 e7 = __builtin_amdgcn_permlane32_swap(pk1[5], pk1[7], 0, 0);
      union { u32 u[4]; s16x8 h; } pf[4];
      pf[0].u[0] = e0.x; pf[0].u[1] = e1.x; pf[0].u[2] = e0.y; pf[0].u[3] = e1.y;
      pf[1].u[0] = e2.x; pf[1].u[1] = e3.x; pf[1].u[2] = e2.y; pf[1].u[3] = e3.y;
      pf[2].u[0] = e4.x; pf[2].u[1] = e5.x; pf[2].u[2] = e4.y; pf[2].u[3] = e5.y;
      pf[3].u[0] = e6.x; pf[3].u[1] = e7.x; pf[3].u[2] = e6.y; pf[3].u[3] = e7.y;

      __builtin_amdgcn_s_setprio(1);
#pragma unroll
      for (int ks = 0; ks < 4; ++ks) {
        int ch = ks * 2 + hi;
        s16x8 av0 = *(const s16x8*)(vp + ql * 64 + ((ch ^ (ql & 7)) * 8));
        s16x8 av1 =
            *(const s16x8*)(vp + (32 + ql) * 64 + ((ch ^ (ql & 7)) * 8));
        o0 = __builtin_amdgcn_mfma_f32_32x32x16_bf16(av0, pf[ks].h, o0, 0, 0,
                                                     0);
        o1 = __builtin_amdgcn_mfma_f32_32x32x16_bf16(av1, pf[ks].h, o1, 0, 0,
                                                     0);
      }
      __builtin_amdgcn_s_setprio(0);
    }
    __syncthreads();
  }

  // epilogue: per-wave LDS transpose of UNNORMALIZED O; write partials
  u16* Zw = &smem[0][0][0][0] + w * (32 * 72);
#pragma unroll
  for (int r = 0; r < 16; r += 2) {
    int d0 = (r & 3) + 8 * (r >> 2) + 4 * hi;
    *(u32*)&Zw[ql * 72 + d0]      = pkbf(o0[r], o0[r + 1]);
    *(u32*)&Zw[ql * 72 + 32 + d0] = pkbf(o1[r], o1[r + 1]);
  }
  if (hi == 0) {
    size_t mix = ((size_t)cc * 32 + bh) * NS + q0w + ql;
    Lpart[mix] = l_run;
  }
#pragma unroll
  for (int i = 0; i < 4; ++i) {
    int cid = i * 64 + l;
    int row = cid >> 3, c8 = (cid & 7) * 8;
    s16x8 vv = *(const s16x8*)&Zw[row * 72 + c8];
    *(s16x8*)(Opart + (((size_t)cc * 32 + bh) * NS + q0w + row) * 64 + c8) =
        vv;
  }
}

// ---------------------------------------------------------------------------
// Combine the 2 KV-split partials (shared fixed m) -> z [B,S,D] bf16.
// ---------------------------------------------------------------------------
__global__ __launch_bounds__(256) void attn_combine_kernel(
    const u16* __restrict__ Opart, const float* __restrict__ Lpart,
    u16* __restrict__ z) {
  const int tok = blockIdx.x;  // 4096 = B*S
  const int bb = tok >> 11, ss = tok & 2047;
  const int t = threadIdx.x;
  const int d4 = t * 4;
  const int hh = d4 >> 6;
  const size_t qix = ((size_t)bb * NH + hh) * NS + ss;
  const size_t stride = (size_t)32 * NS;

  float inv = 1.f / (Lpart[qix] + Lpart[qix + stride]);

  size_t ob = qix * 64 + (d4 & 63);
  uint2 a = *(const uint2*)(Opart + ob);
  uint2 b = *(const uint2*)(Opart + ob + stride * 64);

  float z0 = (bf2f((u16)(a.x & 0xffff)) + bf2f((u16)(b.x & 0xffff))) * inv;
  float z1 = (bf2f((u16)(a.x >> 16)) + bf2f((u16)(b.x >> 16))) * inv;
  float z2 = (bf2f((u16)(a.y & 0xffff)) + bf2f((u16)(b.y & 0xffff))) * inv;
  float z3 = (bf2f((u16)(a.y >> 16)) + bf2f((u16)(b.y >> 16))) * inv;

  uint2 p;
  p.x = pkbf(z0, z1);
  p.y = pkbf(z2, z3);
  *(uint2*)(z + ((size_t)bb * NS + ss) * ND + d4) = p;
}

// ---------------------------------------------------------------------------
// Fallback attn (r5, verified): 1024 blocks x 2 waves, fused causal walk.
// ---------------------------------------------------------------------------
__global__ __launch_bounds__(128) void attn_kernel(
    const u16* __restrict__ qh, const u16* __restrict__ kh,
    const u16* __restrict__ vT, u16* __restrict__ z) {
  const int f = blockIdx.x;
  const int bh = f & 31;
  const int j0 = (f >> 5) & 7;
  const int g = f >> 8;
  const int mb = 2 * j0;
  const int m =
      (g == 0) ? mb : (g == 1) ? mb + 1 : (g == 2) ? 30 - mb : 31 - mb;
  const int bb = bh >> 4, hh = bh & 15;
  const int tid = threadIdx.x;
  const int w = tid >> 6, l = tid & 63;
  const int ql = l & 31, hi = l >> 5, hi8 = hi * 8;
  const int q0w = m * 64 + w * 32;

  __shared__ u16 smem[2][2][64][64];

  s16x8 qf[4];
  {
    const u16* qp = qh + ((size_t)bh * NS + q0w + ql) * 64 + hi8;
#pragma unroll
    for (int st = 0; st < 4; ++st) qf[st] = *(const s16x8*)(qp + st * 16);
  }

  f32x16 o0 = {0, 0, 0, 0, 0, 0, 0, 0, 0, 0, 0, 0, 0, 0, 0, 0};
  f32x16 o1 = {0, 0, 0, 0, 0, 0, 0, 0, 0, 0, 0, 0, 0, 0, 0, 0};
  float m_run = -1e30f, l_run = 0.f;

  const int ntiles = m + 1;

#pragma unroll
  for (int i = 0; i < 4; ++i) {
    int c = i * 128 + tid;
    int row = c >> 3, k8 = (c & 7) ^ (row & 7);
    const u16* sk = kh + ((size_t)bh * NS + row) * 64 + k8 * 8;
    const u16* sv = vT + ((size_t)bh * 64 + row) * NS + k8 * 8;
    u16* dk = &smem[0][0][0][0] + (i * 128 + w * 64) * 8;
    u16* dv = &smem[0][1][0][0] + (i * 128 + w * 64) * 8;
    __builtin_amdgcn_global_load_lds(AS1(sk), AS3(dk), 16, 0, 0);
    __builtin_amdgcn_global_load_lds(AS1(sv), AS3(dv), 16, 0, 0);
  }
  __syncthreads();

  for (int t = 0; t < ntiles; ++t) {
    if (t + 1 < ntiles) {
      int b1 = (t + 1) & 1;
#pragma unroll
      for (int i = 0; i < 4; ++i) {
        int c = i * 128 + tid;
        int row = c >> 3, k8 = (c & 7) ^ (row & 7);
        const u16* sk =
            kh + ((size_t)bh * NS + (t + 1) * 64 + row) * 64 + k8 * 8;
        const u16* sv =
            vT + ((size_t)bh * 64 + row) * NS + (t + 1) * 64 + k8 * 8;
        u16* dk = &smem[b1][0][0][0] + (i * 128 + w * 64) * 8;
        u16* dv = &smem[b1][1][0][0] + (i * 128 + w * 64) * 8;
        __builtin_amdgcn_global_load_lds(AS1(sk), AS3(dk), 16, 0, 0);
        __builtin_amdgcn_global_load_lds(AS1(sv), AS3(dv), 16, 0, 0);
      }
    }
    const u16* kp = &smem[t & 1][0][0][0];
    const u16* vp = &smem[t & 1][1][0][0];

#pragma unroll
    for (int sub = 0; sub < 2; ++sub) {
      const int kvg = t * 64 + sub * 32;
      if (kvg > q0w) continue;
      const bool masked = (kvg == q0w);

      const int kr = sub * 32 + ql;
      f32x16 s = {0, 0, 0, 0, 0, 0, 0, 0, 0, 0, 0, 0, 0, 0, 0, 0};
#pragma unroll
      for (int st = 0; st < 4; ++st) {
        s16x8 ak = *(const s16x8*)(kp + kr * 64 +
                                   (((st * 2 + hi) ^ (kr & 7)) * 8));
        s = __builtin_amdgcn_mfma_f32_32x32x16_bf16(ak, qf[st], s, 0, 0, 0);
      }

      float sv_[16];
#pragma unroll
      for (int r = 0; r < 16; ++r) {
        float x = s[r];
        if (masked) {
          int kvloc = (r & 3) + 8 * (r >> 2) + 4 * hi;
          if (kvloc > ql) x = -1e30f;
        }
        sv_[r] = x;
      }

      float mx = sv_[0];
#pragma unroll
      for (int r = 1; r < 16; ++r) mx = fmaxf(mx, sv_[r]);
      {
        u32x2 rm = __builtin_amdgcn_permlane32_swap(__float_as_uint(mx),
                                                    __float_as_uint(mx), 0, 0);
        mx = fmaxf(__uint_as_float(rm.x), __uint_as_float(rm.y));
      }

      if (__any(mx > m_run)) {
        float mnew = fmaxf(m_run, mx);
        float fs = __builtin_amdgcn_exp2f(m_run - mnew);
#pragma unroll
        for (int r = 0; r < 16; ++r) {
          o0[r] *= fs;
          o1[r] *= fs;
        }
        l_run *= fs;
        m_run = mnew;
      }

      float ps = 0.f;
      u32 pk[8];
#pragma unroll
      for (int tt = 0; tt < 8; ++tt) {
        float a = __builtin_amdgcn_exp2f(sv_[2 * tt] - m_run);
        float b = __builtin_amdgcn_exp2f(sv_[2 * tt + 1] - m_run);
        ps += a + b;
        pk[tt] = pkbf(a, b);
      }
      {
        u32x2 rp = __builtin_amdgcn_permlane32_swap(__float_as_uint(ps),
                                                    __float_as_uint(ps), 0, 0);
        ps = __uint_as_float(rp.x) + __uint_as_float(rp.y);
      }
      l_run += ps;

      u32x2 e0 = __builtin_amdgcn_permlane32_swap(pk[0], pk[2], 0, 0);
      u32x2 e1 = __builtin_amdgcn_permlane32_swap(pk[1], pk[3], 0, 0);
      u32x2 e2 = __builtin_amdgcn_permlane32_swap(pk[4], pk[6], 0, 0);
      u32x2 e3 = __builtin_amdgcn_permlane32_swap(pk[5], pk[7], 0, 0);
      union { u32 u[4]; s16x8 h; } pf0, pf1;
      pf0.u[0] = e0.x; pf0.u[1] = e1.x; pf0.u[2] = e0.y; pf0.u[3] = e1.y;
      pf1.u[0] = e2.x; pf1.u[1] = e3.x; pf1.u[2] = e2.y; pf1.u[3] = e3.y;

#pragma unroll
      for (int k2 = 0; k2 < 2; ++k2) {
        s16x8 pa = (k2 == 0) ? pf0.h : pf1.h;
        int ch = sub * 4 + k2 * 2 + hi;
        s16x8 av0 = *(const s16x8*)(vp + ql * 64 + ((ch ^ (ql & 7)) * 8));
        s16x8 av1 =
            *(const s16x8*)(vp + (32 + ql) * 64 + ((ch ^ (ql & 7)) * 8));
        o0 = __builtin_amdgcn_mfma_f32_32x32x16_bf16(av0, pa, o0, 0, 0, 0);
        o1 = __builtin_amdgcn_mfma_f32_32x32x16_bf16(av1, pa, o1, 0, 0, 0);
      }
    }
    __syncthreads();
  }

  float inv = 1.f / l_run;
  u16* Zw = &smem[0][0][0][0] + w * (32 * 72);
#pragma unroll
  for (int r = 0; r < 16; r += 2) {
    int d0 = (r & 3) + 8 * (r >> 2) + 4 * hi;
    *(u32*)&Zw[ql * 72 + d0]      = pkbf(o0[r] * inv, o0[r + 1] * inv);
    *(u32*)&Zw[ql * 72 + 32 + d0] = pkbf(o1[r] * inv, o1[r + 1] * inv);
  }
#pragma unroll
  for (int i = 0; i < 4; ++i) {
    int cid = i * 64 + l;
    int row = cid >> 3, c8 = (cid & 7) * 8;
    s16x8 vv = *(const s16x8*)&Zw[row * 72 + c8];
    *(s16x8*)(z + ((size_t)bb * NS + q0w + row) * ND + hh * 64 + c8) = vv;
  }
}

// ---------------------------------------------------------------------------
// Fallback (fp32-input) projection kernels.
// ---------------------------------------------------------------------------
__global__ __launch_bounds__(256) void proj_qkv_kernel(
    const float* __restrict__ Qin, const float* __restrict__ Kin,
    const float* __restrict__ Vin,
    const float* __restrict__ Wq, const float* __restrict__ bq,
    const float* __restrict__ Wk, const float* __restrict__ bk,
    const float* __restrict__ Wv, const float* __restrict__ bv,
    u16* __restrict__ qh, u16* __restrict__ kh, u16* __restrict__ vT) {
  const int which = blockIdx.z;
  const float* X = (which == 0) ? Qin : (which == 1) ? Kin : Vin;
  const float* W = (which == 0) ? Wq : (which == 1) ? Wk : Wv;
  const float* bias = (which == 0) ? bq : (which == 1) ? bk : bv;

  const int m0 = blockIdx.y * 128, n0 = blockIdx.x * 128;
  const int tid = threadIdx.x;
  const int w = tid >> 6, l = tid & 63, lr = l & 15, lg = l >> 4;
  const int wr = (w >> 1) * 64, wc = (w & 1) * 64;

  __shared__ u16 As[128][40];
  __shared__ u16 Bs[128][40];

  const f32x4 fzero = {0.f, 0.f, 0.f, 0.f};
  f32x4 acc[4][4];
#pragma unroll
  for (int m = 0; m < 4; ++m)
#pragma unroll
    for (int n = 0; n < 4; ++n) acc[m][n] = fzero;

  for (int k0 = 0; k0 < 1024; k0 += 32) {
#pragma unroll
    for (int i = 0; i < 4; ++i) {
      int idx = tid + i * 256;
      int row = idx >> 3, c4 = (idx & 7) * 4;
      float4 a = *(const float4*)(X + (size_t)(m0 + row) * 1024 + k0 + c4);
      *(u32*)&As[row][c4]     = (u32)f2bf(a.x) | ((u32)f2bf(a.y) << 16);
      *(u32*)&As[row][c4 + 2] = (u32)f2bf(a.z) | ((u32)f2bf(a.w) << 16);
      float4 b = *(const float4*)(W + (size_t)(n0 + row) * 1024 + k0 + c4);
      *(u32*)&Bs[row][c4]     = (u32)f2bf(b.x) | ((u32)f2bf(b.y) << 16);
      *(u32*)&Bs[row][c4 + 2] = (u32)f2bf(b.z) | ((u32)f2bf(b.w) << 16);
    }
    __syncthreads();
    s16x8 af[4], bf[4];
#pragma unroll
    for (int m = 0; m < 4; ++m)
      af[m] = *(const s16x8*)&As[wr + m * 16 + lr][lg * 8];
#pragma unroll
    for (int n = 0; n < 4; ++n)
      bf[n] = *(const s16x8*)&Bs[wc + n * 16 + lr][lg * 8];
#pragma unroll
    for (int m = 0; m < 4; ++m)
#pragma unroll
      for (int n = 0; n < 4; ++n)
        acc[m][n] = __builtin_amdgcn_mfma_f32_16x16x32_bf16(af[m], bf[n],
                                                            acc[m][n], 0, 0, 0);
    __syncthreads();
  }

  u16* dst01 = (which == 0) ? qh : kh;
#pragma unroll
  for (int m = 0; m < 4; ++m) {
#pragma unroll
    for (int n = 0; n < 4; ++n) {
#pragma unroll
      for (int i = 0; i < 4; ++i) {
        int row = m0 + wr + m * 16 + 4 * lg + i;
        int col = n0 + wc + n * 16 + lr;
        float val = acc[m][n][i] + bias[col];
        if (which == 0) val *= QSCALE;
        int bbi = row >> 11, ss = row & 2047;
        int hhd = col >> 6, hd = col & 63;
        if (which < 2) {
          dst01[(((size_t)bbi * NH + hhd) * NS + ss) * 64 + hd] = f2bf(val);
        } else {
          vT[(((size_t)bbi * NH + hhd) * 64 + hd) * NS + ss] = f2bf(val);
        }
      }
    }
  }
}

__global__ __launch_bounds__(256) void proj_out_kernel(
    const u16* __restrict__ zin, const float* __restrict__ Wo,
    const float* __restrict__ bo, float* __restrict__ out) {
  const int m0 = blockIdx.y * 128, n0 = blockIdx.x * 128;
  const int tid = threadIdx.x;
  const int w = tid >> 6, l = tid & 63, lr = l & 15, lg = l >> 4;
  const int wr = (w >> 1) * 64, wc = (w & 1) * 64;

  __shared__ u16 As[128][40];
  __shared__ u16 Bs[128][40];

  const f32x4 fzero = {0.f, 0.f, 0.f, 0.f};
  f32x4 acc[4][4];
#pragma unroll
  for (int m = 0; m < 4; ++m)
#pragma unroll
    for (int n = 0; n < 4; ++n) acc[m][n] = fzero;

  for (int k0 = 0; k0 < 1024; k0 += 32) {
#pragma unroll
    for (int i = 0; i < 2; ++i) {
      int idx = tid + i * 256;
      int row = idx >> 2, c8 = (idx & 3) * 8;
      *(s16x8*)&As[row][c8] =
          *(const s16x8*)(zin + (size_t)(m0 + row) * 1024 + k0 + c8);
    }
#pragma unroll
    for (int i = 0; i < 4; ++i) {
      int idx = tid + i * 256;
      int row = idx >> 3, c4 = (idx & 7) * 4;
      float4 b = *(const float4*)(Wo + (size_t)(n0 + row) * 1024 + k0 + c4);
      *(u32*)&Bs[row][c4]     = (u32)f2bf(b.x) | ((u32)f2bf(b.y) << 16);
      *(u32*)&Bs[row][c4 + 2] = (u32)f2bf(b.z) | ((u32)f2bf(b.w) << 16);
    }
    __syncthreads();
    s16x8 af[4], bf[4];
#pragma unroll
    for (int m = 0; m < 4; ++m)
      af[m] = *(const s16x8*)&As[wr + m * 16 + lr][lg * 8];
#pragma unroll
    for (int n = 0; n < 4; ++n)
      bf[n] = *(const s16x8*)&Bs[wc + n * 16 + lr][lg * 8];
#pragma unroll
    for (int m = 0; m < 4; ++m)
#pragma unroll
      for (int n = 0; n < 4; ++n)
        acc[m][n] = __builtin_amdgcn_mfma_f32_16x16x32_bf16(af[m], bf[n],
                                                            acc[m][n], 0, 0, 0);
    __syncthreads();
  }

#pragma unroll
  for (int m = 0; m < 4; ++m)
#pragma unroll
    for (int n = 0; n < 4; ++n)
#pragma unroll
      for (int i = 0; i < 4; ++i) {
        int row = m0 + wr + m * 16 + 4 * lg + i;
        int col = n0 + wc + n * 16 + lr;
        out[(size_t)row * 1024 + col] = acc[m][n][i] + bo[col];
      }
}

// ---------------------------------------------------------------------------
extern "C" void kernel_launch(void* const* d_in, const int* in_sizes, int n_in,
                              void* d_out, int out_size, void* d_ws,
                              size_t ws_size, hipStream_t stream) {
  const float* Q = (const float*)d_in[0];
  const float* K = (const float*)d_in[1];
  const float* V = (const float*)d_in[2];
  const float* Wq = (const float*)d_in[4];
  const float* bq = (const float*)d_in[5];
  const float* Wk = (const float*)d_in[6];
  const float* bk = (const float*)d_in[7];
  const float* Wv = (const float*)d_in[8];
  const float* bv = (const float*)d_in[9];
  const float* Wo = (const float*)d_in[10];
  const float* bo = (const float*)d_in[11];
  float* out = (float*)d_out;

  const size_t M1 = (size_t)1024 * 1024;
  u16* base = (u16*)d_ws;

  if (ws_size >= (size_t)58720256) {  // fast path: 56 MiB layout
    u16* Wbf = base;                  // [0, 4M) u16
    u16* qh = base + 4 * M1;          // [4M, 8M)
    u16* zz = qh;                     // alias: qh dead before combine writes
    u16* kh = base + 8 * M1;          // [8M, 12M)
    u16* vT = base + 12 * M1;         // [12M, 16M)
    u16* Xbf = base + 16 * M1;        // [16M, 28M), dead after gemm_qkv
    u16* Opart = base + 16 * M1;      // [16M, 24M), alias Xbf
    float* Lpart = (float*)(base + 24 * M1);  // 512 KB

    cvt_kernel<<<dim3(128, 1, 16), 256, 0, stream>>>(Q, K, V, Wq, Wk, Wv, Wo,
                                                     Xbf, Wbf);
    gemm_qkv_fast<<<dim3(8, 64, 3), 256, 0, stream>>>(Xbf, Wbf, bq, bk, bv,
                                                      qh, kh, vT);
    attn_split_kernel<<<dim3(1024), 256, 0, stream>>>(qh, kh, vT, Opart,
                                                      Lpart);
    attn_combine_kernel<<<dim3(4096), 256, 0, stream>>>(Opart, Lpart, zz);
    gemm_out_fast<<<dim3(8, 64), 256, 0, stream>>>(zz, Wbf, bo, out);
  } else {  // fallback: 32 MiB layout (r5 path, verified)
    u16* qh = base;
    u16* kh = base + 4 * M1;
    u16* vT = base + 8 * M1;
    u16* zz = base + 12 * M1;
    proj_qkv_kernel<<<dim3(8, 32, 3), 256, 0, stream>>>(Q, K, V, Wq, bq, Wk,
                                                        bk, Wv, bv, qh, kh, vT);
    attn_kernel<<<dim3(1024), 128, 0, stream>>>(qh, kh, vT, zz);
    proj_out_kernel<<<dim3(8, 32), 256, 0, stream>>>(zz, Wo, bo, out);
  }
}

// Round 20
// 128.065 us; speedup vs baseline: 1.1065x; 1.1065x over previous
//
#include <hip/hip_runtime.h>
#include <hip/hip_bf16.h>

typedef unsigned short u16;
typedef unsigned int u32;
typedef __attribute__((ext_vector_type(2))) unsigned int u32x2;
typedef __attribute__((ext_vector_type(8))) short s16x8;
typedef __attribute__((ext_vector_type(4))) float f32x4;
typedef __attribute__((ext_vector_type(16))) float f32x16;

#define NB 2
#define NH 16
#define NS 2048
#define ND 1024
#define QSCALE 0.1803368801111244f  // 0.125 * log2(e)  (exp2-domain softmax)
#define MFIX 8.0f                   // fixed softmax reference point (exp2 dom)

#define AS1(p) ((const __attribute__((address_space(1))) void*)(p))
#define AS3(p) ((__attribute__((address_space(3))) void*)(p))

__device__ __forceinline__ u16 f2bf(float f) {
  u32 u = __float_as_uint(f);
  u = u + 0x7FFFu + ((u >> 16) & 1u);
  return (u16)(u >> 16);
}

__device__ __forceinline__ float bf2f(u16 h) {
  return __uint_as_float(((u32)h) << 16);
}

__device__ __forceinline__ u32 pkbf(float a, float b) {
  __hip_bfloat162 h = __float22bfloat162_rn(make_float2(a, b));
  union { __hip_bfloat162 h; u32 u; } cv;
  cv.h = h;
  return cv.u;
}

// ---------------------------------------------------------------------------
// fp32 -> bf16 conversion, 16 uniform 1M-element slices.
// ---------------------------------------------------------------------------
__global__ __launch_bounds__(256) void cvt_kernel(
    const float* __restrict__ q, const float* __restrict__ k,
    const float* __restrict__ v, const float* __restrict__ wq,
    const float* __restrict__ wk, const float* __restrict__ wv,
    const float* __restrict__ wo, u16* __restrict__ Xbf,
    u16* __restrict__ Wbf) {
  const int s = blockIdx.z;
  const size_t M1 = (size_t)1024 * 1024;
  const float* src;
  u16* dst;
  if (s < 4)       { src = q + (size_t)s * M1;        dst = Xbf + (size_t)s * M1; }
  else if (s < 8)  { src = k + (size_t)(s - 4) * M1;  dst = Xbf + (size_t)s * M1; }
  else if (s < 12) { src = v + (size_t)(s - 8) * M1;  dst = Xbf + (size_t)s * M1; }
  else if (s == 12){ src = wq; dst = Wbf; }
  else if (s == 13){ src = wk; dst = Wbf + M1; }
  else if (s == 14){ src = wv; dst = Wbf + 2 * M1; }
  else             { src = wo; dst = Wbf + 3 * M1; }
  const int n4 = 1024 * 1024 / 4;
  for (int i = blockIdx.x * 256 + threadIdx.x; i < n4; i += gridDim.x * 256) {
    float4 a = ((const float4*)src)[i];
    uint2 p;
    p.x = (u32)f2bf(a.x) | ((u32)f2bf(a.y) << 16);
    p.y = (u32)f2bf(a.z) | ((u32)f2bf(a.w) << 16);
    ((uint2*)dst)[i] = p;
  }
}

// ---------------------------------------------------------------------------
// 128x128 GEMM, T4 counted-vmcnt 2-deep pipeline (r10/r13, verified best).
// ---------------------------------------------------------------------------
__global__ __launch_bounds__(256) void gemm_qkv_fast(
    const u16* __restrict__ Xbf, const u16* __restrict__ Wbf,
    const float* __restrict__ bq, const float* __restrict__ bk,
    const float* __restrict__ bv, u16* __restrict__ qh, u16* __restrict__ kh,
    u16* __restrict__ vT) {
  const int which = blockIdx.z;
  const int m0 = blockIdx.y * 128, n0 = blockIdx.x * 128;
  const u16* A = Xbf + (size_t)which * 4096 * 1024;
  const u16* B = Wbf + (size_t)which * 1024 * 1024;
  const float* bias = (which == 0) ? bq : (which == 1) ? bk : bv;
  const int tid = threadIdx.x;
  const int w = tid >> 6, l = tid & 63, lr = l & 15, lg = l >> 4;
  const int wr = (w >> 1) * 64, wc = (w & 1) * 64;

  __shared__ u16 As[2][128 * 32];
  __shared__ u16 Bs[2][128 * 32];

  const int c0 = tid, c1 = 256 + tid;
  const int row0 = c0 >> 2, k40 = (c0 & 3) ^ (row0 & 3);
  const int row1 = c1 >> 2, k41 = (c1 & 3) ^ (row1 & 3);
  const u16* sa0 = A + (size_t)(m0 + row0) * 1024 + k40 * 8;
  const u16* sb0 = B + (size_t)(n0 + row0) * 1024 + k40 * 8;
  const u16* sa1 = A + (size_t)(m0 + row1) * 1024 + k41 * 8;
  const u16* sb1 = B + (size_t)(n0 + row1) * 1024 + k41 * 8;
  const int d0 = (w * 64) * 8, d1 = (256 + w * 64) * 8;

  const f32x4 fzero = {0.f, 0.f, 0.f, 0.f};
  f32x4 acc[4][4];
#pragma unroll
  for (int m = 0; m < 4; ++m)
#pragma unroll
    for (int n = 0; n < 4; ++n) acc[m][n] = fzero;

  auto STAGE = [&](int buf, int k0) {
    __builtin_amdgcn_global_load_lds(AS1(sa0 + k0), AS3(As[buf] + d0), 16, 0, 0);
    __builtin_amdgcn_global_load_lds(AS1(sb0 + k0), AS3(Bs[buf] + d0), 16, 0, 0);
    __builtin_amdgcn_global_load_lds(AS1(sa1 + k0), AS3(As[buf] + d1), 16, 0, 0);
    __builtin_amdgcn_global_load_lds(AS1(sb1 + k0), AS3(Bs[buf] + d1), 16, 0, 0);
  };

  STAGE(0, 0);
  STAGE(1, 32);
  asm volatile("s_waitcnt vmcnt(4)" ::: "memory");
  __builtin_amdgcn_sched_barrier(0);
  __builtin_amdgcn_s_barrier();

  int cur = 0;
  for (int step = 0; step < 32; ++step) {
    s16x8 af[4], bf[4];
#pragma unroll
    for (int m = 0; m < 4; ++m) {
      int row = wr + m * 16 + lr;
      af[m] = *(const s16x8*)(As[cur] + row * 32 + ((lg ^ (row & 3)) * 8));
    }
#pragma unroll
    for (int n = 0; n < 4; ++n) {
      int row = wc + n * 16 + lr;
      bf[n] = *(const s16x8*)(Bs[cur] + row * 32 + ((lg ^ (row & 3)) * 8));
    }
    asm volatile("s_waitcnt lgkmcnt(0)" ::: "memory");
    __builtin_amdgcn_sched_barrier(0);
    __builtin_amdgcn_s_barrier();

    const bool stg = (step + 2 < 32);
    if (stg) STAGE(cur, (step + 2) * 32);

    __builtin_amdgcn_s_setprio(1);
#pragma unroll
    for (int m = 0; m < 4; ++m)
#pragma unroll
      for (int n = 0; n < 4; ++n)
        acc[m][n] = __builtin_amdgcn_mfma_f32_16x16x32_bf16(af[m], bf[n],
                                                            acc[m][n], 0, 0, 0);
    __builtin_amdgcn_s_setprio(0);

    if (stg)
      asm volatile("s_waitcnt vmcnt(4)" ::: "memory");
    else
      asm volatile("s_waitcnt vmcnt(0)" ::: "memory");
    __builtin_amdgcn_sched_barrier(0);
    __builtin_amdgcn_s_barrier();
    cur ^= 1;
  }

#pragma unroll
  for (int m = 0; m < 4; ++m) {
#pragma unroll
    for (int n = 0; n < 4; ++n) {
#pragma unroll
      for (int i = 0; i < 4; ++i) {
        int row = m0 + wr + m * 16 + 4 * lg + i;
        int col = n0 + wc + n * 16 + lr;
        float val = acc[m][n][i] + bias[col];
        if (which == 0) val *= QSCALE;
        int bbi = row >> 11, ss = row & 2047;
        int hhd = col >> 6, hd = col & 63;
        if (which == 0) {
          qh[(((size_t)bbi * NH + hhd) * NS + ss) * 64 + hd] = f2bf(val);
        } else if (which == 1) {
          kh[(((size_t)bbi * NH + hhd) * NS + ss) * 64 + hd] = f2bf(val);
        } else {
          vT[(((size_t)bbi * NH + hhd) * 64 + hd) * NS + ss] = f2bf(val);
        }
      }
    }
  }
}

// ---------------------------------------------------------------------------
// Output projection GEMM, same pipeline (r10/r13, verified).
// ---------------------------------------------------------------------------
__global__ __launch_bounds__(256) void gemm_out_fast(
    const u16* __restrict__ zin, const u16* __restrict__ Wbf,
    const float* __restrict__ bo, float* __restrict__ out) {
  const u16* B = Wbf + (size_t)3 * 1024 * 1024;
  const int m0 = blockIdx.y * 128, n0 = blockIdx.x * 128;
  const int tid = threadIdx.x;
  const int w = tid >> 6, l = tid & 63, lr = l & 15, lg = l >> 4;
  const int wr = (w >> 1) * 64, wc = (w & 1) * 64;

  __shared__ u16 As[2][128 * 32];
  __shared__ u16 Bs[2][128 * 32];

  const int c0 = tid, c1 = 256 + tid;
  const int row0 = c0 >> 2, k40 = (c0 & 3) ^ (row0 & 3);
  const int row1 = c1 >> 2, k41 = (c1 & 3) ^ (row1 & 3);
  const u16* sa0 = zin + (size_t)(m0 + row0) * 1024 + k40 * 8;
  const u16* sb0 = B + (size_t)(n0 + row0) * 1024 + k40 * 8;
  const u16* sa1 = zin + (size_t)(m0 + row1) * 1024 + k41 * 8;
  const u16* sb1 = B + (size_t)(n0 + row1) * 1024 + k41 * 8;
  const int d0 = (w * 64) * 8, d1 = (256 + w * 64) * 8;

  const f32x4 fzero = {0.f, 0.f, 0.f, 0.f};
  f32x4 acc[4][4];
#pragma unroll
  for (int m = 0; m < 4; ++m)
#pragma unroll
    for (int n = 0; n < 4; ++n) acc[m][n] = fzero;

  auto STAGE = [&](int buf, int k0) {
    __builtin_amdgcn_global_load_lds(AS1(sa0 + k0), AS3(As[buf] + d0), 16, 0, 0);
    __builtin_amdgcn_global_load_lds(AS1(sb0 + k0), AS3(Bs[buf] + d0), 16, 0, 0);
    __builtin_amdgcn_global_load_lds(AS1(sa1 + k0), AS3(As[buf] + d1), 16, 0, 0);
    __builtin_amdgcn_global_load_lds(AS1(sb1 + k0), AS3(Bs[buf] + d1), 16, 0, 0);
  };

  STAGE(0, 0);
  STAGE(1, 32);
  asm volatile("s_waitcnt vmcnt(4)" ::: "memory");
  __builtin_amdgcn_sched_barrier(0);
  __builtin_amdgcn_s_barrier();

  int cur = 0;
  for (int step = 0; step < 32; ++step) {
    s16x8 af[4], bf[4];
#pragma unroll
    for (int m = 0; m < 4; ++m) {
      int row = wr + m * 16 + lr;
      af[m] = *(const s16x8*)(As[cur] + row * 32 + ((lg ^ (row & 3)) * 8));
    }
#pragma unroll
    for (int n = 0; n < 4; ++n) {
      int row = wc + n * 16 + lr;
      bf[n] = *(const s16x8*)(Bs[cur] + row * 32 + ((lg ^ (row & 3)) * 8));
    }
    asm volatile("s_waitcnt lgkmcnt(0)" ::: "memory");
    __builtin_amdgcn_sched_barrier(0);
    __builtin_amdgcn_s_barrier();

    const bool stg = (step + 2 < 32);
    if (stg) STAGE(cur, (step + 2) * 32);

    __builtin_amdgcn_s_setprio(1);
#pragma unroll
    for (int m = 0; m < 4; ++m)
#pragma unroll
      for (int n = 0; n < 4; ++n)
        acc[m][n] = __builtin_amdgcn_mfma_f32_16x16x32_bf16(af[m], bf[n],
                                                            acc[m][n], 0, 0, 0);
    __builtin_amdgcn_s_setprio(0);

    if (stg)
      asm volatile("s_waitcnt vmcnt(4)" ::: "memory");
    else
      asm volatile("s_waitcnt vmcnt(0)" ::: "memory");
    __builtin_amdgcn_sched_barrier(0);
    __builtin_amdgcn_s_barrier();
    cur ^= 1;
  }

#pragma unroll
  for (int m = 0; m < 4; ++m)
#pragma unroll
    for (int n = 0; n < 4; ++n)
#pragma unroll
      for (int i = 0; i < 4; ++i) {
        int row = m0 + wr + m * 16 + 4 * lg + i;
        int col = n0 + wc + n * 16 + lr;
        out[(size_t)row * 1024 + col] = acc[m][n][i] + bo[col];
      }
}

// ---------------------------------------------------------------------------
// KV-split causal flash attention, fixed-m softmax. ONE CHUNK PER BLOCK:
// grid 1024 -> 4 blocks/CU residency. Decode: len = 16-(f>>6)
// (longest-first), bh = (f&63)>>1, cc = f&1, band = len-1,
// tiles [t0,t1) = cc ? [len,2len) : [0,len).
// ---------------------------------------------------------------------------
__device__ __forceinline__ void stage64(const u16* __restrict__ kh,
                                        const u16* __restrict__ vT, int bh,
                                        int t, int tid, int w, u16* kbase,
                                        u16* vbase) {
#pragma unroll
  for (int i = 0; i < 2; ++i) {
    int c = i * 256 + tid;
    int row = c >> 3, k8 = (c & 7) ^ (row & 7);
    const u16* sk = kh + ((size_t)bh * NS + t * 64 + row) * 64 + k8 * 8;
    const u16* sv = vT + ((size_t)bh * 64 + row) * NS + t * 64 + k8 * 8;
    u16* dk = kbase + (i * 256 + w * 64) * 8;
    u16* dv = vbase + (i * 256 + w * 64) * 8;
    __builtin_amdgcn_global_load_lds(AS1(sk), AS3(dk), 16, 0, 0);
    __builtin_amdgcn_global_load_lds(AS1(sv), AS3(dv), 16, 0, 0);
  }
}

__global__ __launch_bounds__(256) void attn_split_kernel(
    const u16* __restrict__ qh, const u16* __restrict__ kh,
    const u16* __restrict__ vT, u16* __restrict__ Opart,
    float* __restrict__ Lpart) {
  const int f = blockIdx.x;             // 0..1023
  const int len = 16 - (f >> 6);        // 16..1, longest chunks first
  const int idx = f & 63;
  const int bh = idx >> 1;              // 0..31
  const int cc = idx & 1;               // partial slot
  const int band = len - 1;             // q band (128 rows)
  const int t0 = cc ? len : 0;
  const int t1 = t0 + len;
  const int tid = threadIdx.x;
  const int w = tid >> 6, l = tid & 63;
  const int ql = l & 31, hi = l >> 5, hi8 = hi * 8;
  const int q0w = band * 128 + w * 32;

  __shared__ u16 smem[2][2][64][64];  // [buf][K/V][row][64] linear, swizzled

  s16x8 qf[4];
  {
    const u16* qp = qh + ((size_t)bh * NS + q0w + ql) * 64 + hi8;
#pragma unroll
    for (int st = 0; st < 4; ++st) qf[st] = *(const s16x8*)(qp + st * 16);
  }

  f32x16 o0 = {0, 0, 0, 0, 0, 0, 0, 0, 0, 0, 0, 0, 0, 0, 0, 0};
  f32x16 o1 = {0, 0, 0, 0, 0, 0, 0, 0, 0, 0, 0, 0, 0, 0, 0, 0};
  float l_run = 0.f;

  stage64(kh, vT, bh, t0, tid, w, &smem[t0 & 1][0][0][0],
          &smem[t0 & 1][1][0][0]);
  __syncthreads();

  for (int t = t0; t < t1; ++t) {
    if (t + 1 < t1)
      stage64(kh, vT, bh, t + 1, tid, w, &smem[(t + 1) & 1][0][0][0],
              &smem[(t + 1) & 1][1][0][0]);
    const u16* kp = &smem[t & 1][0][0][0];
    const u16* vp = &smem[t & 1][1][0][0];

    const int kvg0 = t * 64, kvg1 = t * 64 + 32;
    if (kvg0 <= q0w) {  // wave-uniform; whole-tile skip only at chunk tail
      f32x16 s0 = {0, 0, 0, 0, 0, 0, 0, 0, 0, 0, 0, 0, 0, 0, 0, 0};
      f32x16 s1 = {0, 0, 0, 0, 0, 0, 0, 0, 0, 0, 0, 0, 0, 0, 0, 0};
      const int kr0 = ql, kr1 = 32 + ql;
      __builtin_amdgcn_s_setprio(1);
#pragma unroll
      for (int st = 0; st < 4; ++st) {
        s16x8 ak = *(const s16x8*)(kp + kr0 * 64 +
                                   (((st * 2 + hi) ^ (kr0 & 7)) * 8));
        s0 = __builtin_amdgcn_mfma_f32_32x32x16_bf16(ak, qf[st], s0, 0, 0, 0);
      }
      if (kvg1 <= q0w) {
#pragma unroll
        for (int st = 0; st < 4; ++st) {
          s16x8 ak = *(const s16x8*)(kp + kr1 * 64 +
                                     (((st * 2 + hi) ^ (kr1 & 7)) * 8));
          s1 = __builtin_amdgcn_mfma_f32_32x32x16_bf16(ak, qf[st], s1, 0, 0,
                                                       0);
        }
      }
      __builtin_amdgcn_s_setprio(0);

      if (kvg0 == q0w) {
#pragma unroll
        for (int r = 0; r < 16; ++r) {
          int kvloc = (r & 3) + 8 * (r >> 2) + 4 * hi;
          if (kvloc > ql) s0[r] = -1e30f;
        }
      }
      if (kvg1 > q0w) {
#pragma unroll
        for (int r = 0; r < 16; ++r) s1[r] = -1e30f;
      } else if (kvg1 == q0w) {
#pragma unroll
        for (int r = 0; r < 16; ++r) {
          int kvloc = (r & 3) + 8 * (r >> 2) + 4 * hi;
          if (kvloc > ql) s1[r] = -1e30f;
        }
      }

      // ---- fixed-m softmax: P = exp2(S - MFIX); no max, no rescale ----
      float ps = 0.f;
      u32 pk0[8], pk1[8];
#pragma unroll
      for (int tt = 0; tt < 8; ++tt) {
        float a = __builtin_amdgcn_exp2f(s0[2 * tt] - MFIX);
        float b = __builtin_amdgcn_exp2f(s0[2 * tt + 1] - MFIX);
        ps += a + b;
        pk0[tt] = pkbf(a, b);
      }
#pragma unroll
      for (int tt = 0; tt < 8; ++tt) {
        float a = __builtin_amdgcn_exp2f(s1[2 * tt] - MFIX);
        float b = __builtin_amdgcn_exp2f(s1[2 * tt + 1] - MFIX);
        ps += a + b;
        pk1[tt] = pkbf(a, b);
      }
      {
        u32x2 rp = __builtin_amdgcn_permlane32_swap(
            __float_as_uint(ps), __float_as_uint(ps), 0, 0);
        ps = __uint_as_float(rp.x) + __uint_as_float(rp.y);
      }
      l_run += ps;

      u32x2 e0 = __builtin_amdgcn_permlane32_swap(pk0[0], pk0[2], 0, 0);
      u32x2 e1 = __builtin_amdgcn_permlane32_swap(pk0[1], pk0[3], 0, 0);
      u32x2 e2 = __builtin_amdgcn_permlane32_swap(pk0[4], pk0[6], 0, 0);
      u32x2 e3 = __builtin_amdgcn_permlane32_swap(pk0[5], pk0[7], 0, 0);
      u32x2 e4 = __builtin_amdgcn_permlane32_swap(pk1[0], pk1[2], 0, 0);
      u32x2 e5 = __builtin_amdgcn_permlane32_swap(pk1[1], pk1[3], 0, 0);
      u32x2 e6 = __builtin_amdgcn_permlane32_swap(pk1[4], pk1[6], 0, 0);
      u32x2 e7 = __builtin_amdgcn_permlane32_swap(pk1[5], pk1[7], 0, 0);
      union { u32 u[4]; s16x8 h; } pf[4];
      pf[0].u[0] = e0.x; pf[0].u[1] = e1.x; pf[0].u[2] = e0.y; pf[0].u[3] = e1.y;
      pf[1].u[0] = e2.x; pf[1].u[1] = e3.x; pf[1].u[2] = e2.y; pf[1].u[3] = e3.y;
      pf[2].u[0] = e4.x; pf[2].u[1] = e5.x; pf[2].u[2] = e4.y; pf[2].u[3] = e5.y;
      pf[3].u[0] = e6.x; pf[3].u[1] = e7.x; pf[3].u[2] = e6.y; pf[3].u[3] = e7.y;

      __builtin_amdgcn_s_setprio(1);
#pragma unroll
      for (int ks = 0; ks < 4; ++ks) {
        int ch = ks * 2 + hi;
        s16x8 av0 = *(const s16x8*)(vp + ql * 64 + ((ch ^ (ql & 7)) * 8));
        s16x8 av1 =
            *(const s16x8*)(vp + (32 + ql) * 64 + ((ch ^ (ql & 7)) * 8));
        o0 = __builtin_amdgcn_mfma_f32_32x32x16_bf16(av0, pf[ks].h, o0, 0, 0,
                                                     0);
        o1 = __builtin_amdgcn_mfma_f32_32x32x16_bf16(av1, pf[ks].h, o1, 0, 0,
                                                     0);
      }
      __builtin_amdgcn_s_setprio(0);
    }
    __syncthreads();
  }

  // epilogue: per-wave LDS transpose of UNNORMALIZED O; write partials
  u16* Zw = &smem[0][0][0][0] + w * (32 * 72);
#pragma unroll
  for (int r = 0; r < 16; r += 2) {
    int d0 = (r & 3) + 8 * (r >> 2) + 4 * hi;
    *(u32*)&Zw[ql * 72 + d0]      = pkbf(o0[r], o0[r + 1]);
    *(u32*)&Zw[ql * 72 + 32 + d0] = pkbf(o1[r], o1[r + 1]);
  }
  if (hi == 0) {
    size_t mix = ((size_t)cc * 32 + bh) * NS + q0w + ql;
    Lpart[mix] = l_run;
  }
#pragma unroll
  for (int i = 0; i < 4; ++i) {
    int cid = i * 64 + l;
    int row = cid >> 3, c8 = (cid & 7) * 8;
    s16x8 vv = *(const s16x8*)&Zw[row * 72 + c8];
    *(s16x8*)(Opart + (((size_t)cc * 32 + bh) * NS + q0w + row) * 64 + c8) =
        vv;
  }
}

// ---------------------------------------------------------------------------
// Combine the 2 KV-split partials (shared fixed m) -> z [B,S,D] bf16.
// ---------------------------------------------------------------------------
__global__ __launch_bounds__(256) void attn_combine_kernel(
    const u16* __restrict__ Opart, const float* __restrict__ Lpart,
    u16* __restrict__ z) {
  const int tok = blockIdx.x;  // 4096 = B*S
  const int bb = tok >> 11, ss = tok & 2047;
  const int t = threadIdx.x;
  const int d4 = t * 4;
  const int hh = d4 >> 6;
  const size_t qix = ((size_t)bb * NH + hh) * NS + ss;
  const size_t stride = (size_t)32 * NS;

  float inv = 1.f / (Lpart[qix] + Lpart[qix + stride]);

  size_t ob = qix * 64 + (d4 & 63);
  uint2 a = *(const uint2*)(Opart + ob);
  uint2 b = *(const uint2*)(Opart + ob + stride * 64);

  float z0 = (bf2f((u16)(a.x & 0xffff)) + bf2f((u16)(b.x & 0xffff))) * inv;
  float z1 = (bf2f((u16)(a.x >> 16)) + bf2f((u16)(b.x >> 16))) * inv;
  float z2 = (bf2f((u16)(a.y & 0xffff)) + bf2f((u16)(b.y & 0xffff))) * inv;
  float z3 = (bf2f((u16)(a.y >> 16)) + bf2f((u16)(b.y >> 16))) * inv;

  uint2 p;
  p.x = pkbf(z0, z1);
  p.y = pkbf(z2, z3);
  *(uint2*)(z + ((size_t)bb * NS + ss) * ND + d4) = p;
}

// ---------------------------------------------------------------------------
// Fallback attn (r5, verified): 1024 blocks x 2 waves, fused causal walk.
// ---------------------------------------------------------------------------
__global__ __launch_bounds__(128) void attn_kernel(
    const u16* __restrict__ qh, const u16* __restrict__ kh,
    const u16* __restrict__ vT, u16* __restrict__ z) {
  const int f = blockIdx.x;
  const int bh = f & 31;
  const int j0 = (f >> 5) & 7;
  const int g = f >> 8;
  const int mb = 2 * j0;
  const int m =
      (g == 0) ? mb : (g == 1) ? mb + 1 : (g == 2) ? 30 - mb : 31 - mb;
  const int bb = bh >> 4, hh = bh & 15;
  const int tid = threadIdx.x;
  const int w = tid >> 6, l = tid & 63;
  const int ql = l & 31, hi = l >> 5, hi8 = hi * 8;
  const int q0w = m * 64 + w * 32;

  __shared__ u16 smem[2][2][64][64];

  s16x8 qf[4];
  {
    const u16* qp = qh + ((size_t)bh * NS + q0w + ql) * 64 + hi8;
#pragma unroll
    for (int st = 0; st < 4; ++st) qf[st] = *(const s16x8*)(qp + st * 16);
  }

  f32x16 o0 = {0, 0, 0, 0, 0, 0, 0, 0, 0, 0, 0, 0, 0, 0, 0, 0};
  f32x16 o1 = {0, 0, 0, 0, 0, 0, 0, 0, 0, 0, 0, 0, 0, 0, 0, 0};
  float m_run = -1e30f, l_run = 0.f;

  const int ntiles = m + 1;

#pragma unroll
  for (int i = 0; i < 4; ++i) {
    int c = i * 128 + tid;
    int row = c >> 3, k8 = (c & 7) ^ (row & 7);
    const u16* sk = kh + ((size_t)bh * NS + row) * 64 + k8 * 8;
    const u16* sv = vT + ((size_t)bh * 64 + row) * NS + k8 * 8;
    u16* dk = &smem[0][0][0][0] + (i * 128 + w * 64) * 8;
    u16* dv = &smem[0][1][0][0] + (i * 128 + w * 64) * 8;
    __builtin_amdgcn_global_load_lds(AS1(sk), AS3(dk), 16, 0, 0);
    __builtin_amdgcn_global_load_lds(AS1(sv), AS3(dv), 16, 0, 0);
  }
  __syncthreads();

  for (int t = 0; t < ntiles; ++t) {
    if (t + 1 < ntiles) {
      int b1 = (t + 1) & 1;
#pragma unroll
      for (int i = 0; i < 4; ++i) {
        int c = i * 128 + tid;
        int row = c >> 3, k8 = (c & 7) ^ (row & 7);
        const u16* sk =
            kh + ((size_t)bh * NS + (t + 1) * 64 + row) * 64 + k8 * 8;
        const u16* sv =
            vT + ((size_t)bh * 64 + row) * NS + (t + 1) * 64 + k8 * 8;
        u16* dk = &smem[b1][0][0][0] + (i * 128 + w * 64) * 8;
        u16* dv = &smem[b1][1][0][0] + (i * 128 + w * 64) * 8;
        __builtin_amdgcn_global_load_lds(AS1(sk), AS3(dk), 16, 0, 0);
        __builtin_amdgcn_global_load_lds(AS1(sv), AS3(dv), 16, 0, 0);
      }
    }
    const u16* kp = &smem[t & 1][0][0][0];
    const u16* vp = &smem[t & 1][1][0][0];

#pragma unroll
    for (int sub = 0; sub < 2; ++sub) {
      const int kvg = t * 64 + sub * 32;
      if (kvg > q0w) continue;
      const bool masked = (kvg == q0w);

      const int kr = sub * 32 + ql;
      f32x16 s = {0, 0, 0, 0, 0, 0, 0, 0, 0, 0, 0, 0, 0, 0, 0, 0};
#pragma unroll
      for (int st = 0; st < 4; ++st) {
        s16x8 ak = *(const s16x8*)(kp + kr * 64 +
                                   (((st * 2 + hi) ^ (kr & 7)) * 8));
        s = __builtin_amdgcn_mfma_f32_32x32x16_bf16(ak, qf[st], s, 0, 0, 0);
      }

      float sv_[16];
#pragma unroll
      for (int r = 0; r < 16; ++r) {
        float x = s[r];
        if (masked) {
          int kvloc = (r & 3) + 8 * (r >> 2) + 4 * hi;
          if (kvloc > ql) x = -1e30f;
        }
        sv_[r] = x;
      }

      float mx = sv_[0];
#pragma unroll
      for (int r = 1; r < 16; ++r) mx = fmaxf(mx, sv_[r]);
      {
        u32x2 rm = __builtin_amdgcn_permlane32_swap(__float_as_uint(mx),
                                                    __float_as_uint(mx), 0, 0);
        mx = fmaxf(__uint_as_float(rm.x), __uint_as_float(rm.y));
      }

      if (__any(mx > m_run)) {
        float mnew = fmaxf(m_run, mx);
        float fs = __builtin_amdgcn_exp2f(m_run - mnew);
#pragma unroll
        for (int r = 0; r < 16; ++r) {
          o0[r] *= fs;
          o1[r] *= fs;
        }
        l_run *= fs;
        m_run = mnew;
      }

      float ps = 0.f;
      u32 pk[8];
#pragma unroll
      for (int tt = 0; tt < 8; ++tt) {
        float a = __builtin_amdgcn_exp2f(sv_[2 * tt] - m_run);
        float b = __builtin_amdgcn_exp2f(sv_[2 * tt + 1] - m_run);
        ps += a + b;
        pk[tt] = pkbf(a, b);
      }
      {
        u32x2 rp = __builtin_amdgcn_permlane32_swap(__float_as_uint(ps),
                                                    __float_as_uint(ps), 0, 0);
        ps = __uint_as_float(rp.x) + __uint_as_float(rp.y);
      }
      l_run += ps;

      u32x2 e0 = __builtin_amdgcn_permlane32_swap(pk[0], pk[2], 0, 0);
      u32x2 e1 = __builtin_amdgcn_permlane32_swap(pk[1], pk[3], 0, 0);
      u32x2 e2 = __builtin_amdgcn_permlane32_swap(pk[4], pk[6], 0, 0);
      u32x2 e3 = __builtin_amdgcn_permlane32_swap(pk[5], pk[7], 0, 0);
      union { u32 u[4]; s16x8 h; } pf0, pf1;
      pf0.u[0] = e0.x; pf0.u[1] = e1.x; pf0.u[2] = e0.y; pf0.u[3] = e1.y;
      pf1.u[0] = e2.x; pf1.u[1] = e3.x; pf1.u[2] = e2.y; pf1.u[3] = e3.y;

#pragma unroll
      for (int k2 = 0; k2 < 2; ++k2) {
        s16x8 pa = (k2 == 0) ? pf0.h : pf1.h;
        int ch = sub * 4 + k2 * 2 + hi;
        s16x8 av0 = *(const s16x8*)(vp + ql * 64 + ((ch ^ (ql & 7)) * 8));
        s16x8 av1 =
            *(const s16x8*)(vp + (32 + ql) * 64 + ((ch ^ (ql & 7)) * 8));
        o0 = __builtin_amdgcn_mfma_f32_32x32x16_bf16(av0, pa, o0, 0, 0, 0);
        o1 = __builtin_amdgcn_mfma_f32_32x32x16_bf16(av1, pa, o1, 0, 0, 0);
      }
    }
    __syncthreads();
  }

  float inv = 1.f / l_run;
  u16* Zw = &smem[0][0][0][0] + w * (32 * 72);
#pragma unroll
  for (int r = 0; r < 16; r += 2) {
    int d0 = (r & 3) + 8 * (r >> 2) + 4 * hi;
    *(u32*)&Zw[ql * 72 + d0]      = pkbf(o0[r] * inv, o0[r + 1] * inv);
    *(u32*)&Zw[ql * 72 + 32 + d0] = pkbf(o1[r] * inv, o1[r + 1] * inv);
  }
#pragma unroll
  for (int i = 0; i < 4; ++i) {
    int cid = i * 64 + l;
    int row = cid >> 3, c8 = (cid & 7) * 8;
    s16x8 vv = *(const s16x8*)&Zw[row * 72 + c8];
    *(s16x8*)(z + ((size_t)bb * NS + q0w + row) * ND + hh * 64 + c8) = vv;
  }
}

// ---------------------------------------------------------------------------
// Fallback (fp32-input) projection kernels.
// ---------------------------------------------------------------------------
__global__ __launch_bounds__(256) void proj_qkv_kernel(
    const float* __restrict__ Qin, const float* __restrict__ Kin,
    const float* __restrict__ Vin,
    const float* __restrict__ Wq, const float* __restrict__ bq,
    const float* __restrict__ Wk, const float* __restrict__ bk,
    const float* __restrict__ Wv, const float* __restrict__ bv,
    u16* __restrict__ qh, u16* __restrict__ kh, u16* __restrict__ vT) {
  const int which = blockIdx.z;
  const float* X = (which == 0) ? Qin : (which == 1) ? Kin : Vin;
  const float* W = (which == 0) ? Wq : (which == 1) ? Wk : Wv;
  const float* bias = (which == 0) ? bq : (which == 1) ? bk : bv;

  const int m0 = blockIdx.y * 128, n0 = blockIdx.x * 128;
  const int tid = threadIdx.x;
  const int w = tid >> 6, l = tid & 63, lr = l & 15, lg = l >> 4;
  const int wr = (w >> 1) * 64, wc = (w & 1) * 64;

  __shared__ u16 As[128][40];
  __shared__ u16 Bs[128][40];

  const f32x4 fzero = {0.f, 0.f, 0.f, 0.f};
  f32x4 acc[4][4];
#pragma unroll
  for (int m = 0; m < 4; ++m)
#pragma unroll
    for (int n = 0; n < 4; ++n) acc[m][n] = fzero;

  for (int k0 = 0; k0 < 1024; k0 += 32) {
#pragma unroll
    for (int i = 0; i < 4; ++i) {
      int idx = tid + i * 256;
      int row = idx >> 3, c4 = (idx & 7) * 4;
      float4 a = *(const float4*)(X + (size_t)(m0 + row) * 1024 + k0 + c4);
      *(u32*)&As[row][c4]     = (u32)f2bf(a.x) | ((u32)f2bf(a.y) << 16);
      *(u32*)&As[row][c4 + 2] = (u32)f2bf(a.z) | ((u32)f2bf(a.w) << 16);
      float4 b = *(const float4*)(W + (size_t)(n0 + row) * 1024 + k0 + c4);
      *(u32*)&Bs[row][c4]     = (u32)f2bf(b.x) | ((u32)f2bf(b.y) << 16);
      *(u32*)&Bs[row][c4 + 2] = (u32)f2bf(b.z) | ((u32)f2bf(b.w) << 16);
    }
    __syncthreads();
    s16x8 af[4], bf[4];
#pragma unroll
    for (int m = 0; m < 4; ++m)
      af[m] = *(const s16x8*)&As[wr + m * 16 + lr][lg * 8];
#pragma unroll
    for (int n = 0; n < 4; ++n)
      bf[n] = *(const s16x8*)&Bs[wc + n * 16 + lr][lg * 8];
#pragma unroll
    for (int m = 0; m < 4; ++m)
#pragma unroll
      for (int n = 0; n < 4; ++n)
        acc[m][n] = __builtin_amdgcn_mfma_f32_16x16x32_bf16(af[m], bf[n],
                                                            acc[m][n], 0, 0, 0);
    __syncthreads();
  }

  u16* dst01 = (which == 0) ? qh : kh;
#pragma unroll
  for (int m = 0; m < 4; ++m) {
#pragma unroll
    for (int n = 0; n < 4; ++n) {
#pragma unroll
      for (int i = 0; i < 4; ++i) {
        int row = m0 + wr + m * 16 + 4 * lg + i;
        int col = n0 + wc + n * 16 + lr;
        float val = acc[m][n][i] + bias[col];
        if (which == 0) val *= QSCALE;
        int bbi = row >> 11, ss = row & 2047;
        int hhd = col >> 6, hd = col & 63;
        if (which < 2) {
          dst01[(((size_t)bbi * NH + hhd) * NS + ss) * 64 + hd] = f2bf(val);
        } else {
          vT[(((size_t)bbi * NH + hhd) * 64 + hd) * NS + ss] = f2bf(val);
        }
      }
    }
  }
}

__global__ __launch_bounds__(256) void proj_out_kernel(
    const u16* __restrict__ zin, const float* __restrict__ Wo,
    const float* __restrict__ bo, float* __restrict__ out) {
  const int m0 = blockIdx.y * 128, n0 = blockIdx.x * 128;
  const int tid = threadIdx.x;
  const int w = tid >> 6, l = tid & 63, lr = l & 15, lg = l >> 4;
  const int wr = (w >> 1) * 64, wc = (w & 1) * 64;

  __shared__ u16 As[128][40];
  __shared__ u16 Bs[128][40];

  const f32x4 fzero = {0.f, 0.f, 0.f, 0.f};
  f32x4 acc[4][4];
#pragma unroll
  for (int m = 0; m < 4; ++m)
#pragma unroll
    for (int n = 0; n < 4; ++n) acc[m][n] = fzero;

  for (int k0 = 0; k0 < 1024; k0 += 32) {
#pragma unroll
    for (int i = 0; i < 2; ++i) {
      int idx = tid + i * 256;
      int row = idx >> 2, c8 = (idx & 3) * 8;
      *(s16x8*)&As[row][c8] =
          *(const s16x8*)(zin + (size_t)(m0 + row) * 1024 + k0 + c8);
    }
#pragma unroll
    for (int i = 0; i < 4; ++i) {
      int idx = tid + i * 256;
      int row = idx >> 3, c4 = (idx & 7) * 4;
      float4 b = *(const float4*)(Wo + (size_t)(n0 + row) * 1024 + k0 + c4);
      *(u32*)&Bs[row][c4]     = (u32)f2bf(b.x) | ((u32)f2bf(b.y) << 16);
      *(u32*)&Bs[row][c4 + 2] = (u32)f2bf(b.z) | ((u32)f2bf(b.w) << 16);
    }
    __syncthreads();
    s16x8 af[4], bf[4];
#pragma unroll
    for (int m = 0; m < 4; ++m)
      af[m] = *(const s16x8*)&As[wr + m * 16 + lr][lg * 8];
#pragma unroll
    for (int n = 0; n < 4; ++n)
      bf[n] = *(const s16x8*)&Bs[wc + n * 16 + lr][lg * 8];
#pragma unroll
    for (int m = 0; m < 4; ++m)
#pragma unroll
      for (int n = 0; n < 4; ++n)
        acc[m][n] = __builtin_amdgcn_mfma_f32_16x16x32_bf16(af[m], bf[n],
                                                            acc[m][n], 0, 0, 0);
    __syncthreads();
  }

#pragma unroll
  for (int m = 0; m < 4; ++m)
#pragma unroll
    for (int n = 0; n < 4; ++n)
#pragma unroll
      for (int i = 0; i < 4; ++i) {
        int row = m0 + wr + m * 16 + 4 * lg + i;
        int col = n0 + wc + n * 16 + lr;
        out[(size_t)row * 1024 + col] = acc[m][n][i] + bo[col];
      }
}

// ---------------------------------------------------------------------------
extern "C" void kernel_launch(void* const* d_in, const int* in_sizes, int n_in,
                              void* d_out, int out_size, void* d_ws,
                              size_t ws_size, hipStream_t stream) {
  const float* Q = (const float*)d_in[0];
  const float* K = (const float*)d_in[1];
  const float* V = (const float*)d_in[2];
  const float* Wq = (const float*)d_in[4];
  const float* bq = (const float*)d_in[5];
  const float* Wk = (const float*)d_in[6];
  const float* bk = (const float*)d_in[7];
  const float* Wv = (const float*)d_in[8];
  const float* bv = (const float*)d_in[9];
  const float* Wo = (const float*)d_in[10];
  const float* bo = (const float*)d_in[11];
  float* out = (float*)d_out;

  const size_t M1 = (size_t)1024 * 1024;
  u16* base = (u16*)d_ws;

  if (ws_size >= (size_t)58720256) {  // fast path: 56 MiB layout
    u16* Wbf = base;                  // [0, 4M) u16
    u16* qh = base + 4 * M1;          // [4M, 8M)
    u16* zz = qh;                     // alias: qh dead before combine writes
    u16* kh = base + 8 * M1;          // [8M, 12M)
    u16* vT = base + 12 * M1;         // [12M, 16M)
    u16* Xbf = base + 16 * M1;        // [16M, 28M), dead after gemm_qkv
    u16* Opart = base + 16 * M1;      // [16M, 24M), alias Xbf
    float* Lpart = (float*)(base + 24 * M1);  // 512 KB

    cvt_kernel<<<dim3(128, 1, 16), 256, 0, stream>>>(Q, K, V, Wq, Wk, Wv, Wo,
                                                     Xbf, Wbf);
    gemm_qkv_fast<<<dim3(8, 32, 3), 256, 0, stream>>>(Xbf, Wbf, bq, bk, bv,
                                                      qh, kh, vT);
    attn_split_kernel<<<dim3(1024), 256, 0, stream>>>(qh, kh, vT, Opart,
                                                      Lpart);
    attn_combine_kernel<<<dim3(4096), 256, 0, stream>>>(Opart, Lpart, zz);
    gemm_out_fast<<<dim3(8, 32), 256, 0, stream>>>(zz, Wbf, bo, out);
  } else {  // fallback: 32 MiB layout (r5 path, verified)
    u16* qh = base;
    u16* kh = base + 4 * M1;
    u16* vT = base + 8 * M1;
    u16* zz = base + 12 * M1;
    proj_qkv_kernel<<<dim3(8, 32, 3), 256, 0, stream>>>(Q, K, V, Wq, bq, Wk,
                                                        bk, Wv, bv, qh, kh, vT);
    attn_kernel<<<dim3(1024), 128, 0, stream>>>(qh, kh, vT, zz);
    proj_out_kernel<<<dim3(8, 32), 256, 0, stream>>>(zz, Wo, bo, out);
  }
}